// Round 1
// 2615.776 us; speedup vs baseline: 1.1960x; 1.1960x over previous
//
#include <hip/hip_runtime.h>
#include <hip/hip_bf16.h>

typedef __hip_bfloat16 bf16;
typedef __attribute__((ext_vector_type(8))) short s16x8;
typedef __attribute__((ext_vector_type(4))) short s16x4;
typedef __attribute__((ext_vector_type(4))) float f32x4;

#define NEG_INF (-__builtin_inff())

union V8 { s16x8 v8; s16x4 v4[2]; };

__device__ inline s16x8 ldfrag(const bf16* p) {
    V8 f;
    f.v4[0] = *(const s16x4*)p;
    f.v4[1] = *(const s16x4*)(p + 4);
    return f.v8;
}

__device__ inline unsigned short f2bu(float f) {
    union { bf16 b; unsigned short u; } c;
    c.b = __float2bfloat16(f);
    return c.u;
}

__device__ inline float bu2f(unsigned short u) {
    union { bf16 b; unsigned short u; } c;
    c.u = u;
    return __bfloat162float(c.b);
}

// global -> LDS direct copy, 16B per lane. LDS dest must be wave-uniform base;
// HW writes lane i at base + i*16 (CK-style addrspace cast via integer).
__device__ inline void gload16(const bf16* gsrc, const bf16* ldst) {
    __builtin_amdgcn_global_load_lds(
        (const __attribute__((address_space(1))) unsigned int*)(unsigned long long)gsrc,
        (__attribute__((address_space(3))) unsigned int*)(unsigned int)(unsigned long long)ldst,
        16, 0, 0);
}

// ---------------------------------------------------------------- dtype sniff
__global__ void sniff_kernel(const unsigned short* __restrict__ tok, int* __restrict__ flag)
{
    int big = 0;
    for (int i = threadIdx.x; i < 2048; i += 64) {
        unsigned e = (tok[i] >> 7) & 0xFFu;
        if (e >= 127u) big++;
    }
    #pragma unroll
    for (int off = 32; off; off >>= 1) big += __shfl_down(big, off);
    if (threadIdx.x == 0) *flag = (big > 64) ? 1 : 0;
}

// ---------------------------------------------------------------- weight prep
// out[N][K] bf16 = transpose(in[K][N]) with fp32-or-bf16 input. 32x32 tiles.
__global__ __launch_bounds__(256) void transpose_cvt_kernel(
    const void* __restrict__ in, bf16* __restrict__ out,
    int N, int K, long in_bs, long out_bs, const int* __restrict__ flag)
{
    __shared__ float tile[32][33];
    const int f32 = *flag;
    const int z = blockIdx.z;
    const int n0 = blockIdx.x * 32, k0 = blockIdx.y * 32;
    const int r  = threadIdx.x >> 3;
    const int c4 = (threadIdx.x & 7) * 4;
    if (f32) {
        const float* ip = (const float*)in + z * in_bs;
        float4 v = *(const float4*)(ip + (long)(k0 + r) * N + n0 + c4);
        tile[r][c4 + 0] = v.x; tile[r][c4 + 1] = v.y;
        tile[r][c4 + 2] = v.z; tile[r][c4 + 3] = v.w;
    } else {
        const bf16* ip = (const bf16*)in + z * in_bs;
        ushort4 v = *(const ushort4*)(ip + (long)(k0 + r) * N + n0 + c4);
        tile[r][c4 + 0] = bu2f(v.x); tile[r][c4 + 1] = bu2f(v.y);
        tile[r][c4 + 2] = bu2f(v.z); tile[r][c4 + 3] = bu2f(v.w);
    }
    __syncthreads();
    bf16* op = out + z * out_bs;
    ushort4 o;
    o.x = f2bu(tile[c4 + 0][r]); o.y = f2bu(tile[c4 + 1][r]);
    o.z = f2bu(tile[c4 + 2][r]); o.w = f2bu(tile[c4 + 3][r]);
    *(ushort4*)(op + (long)(n0 + r) * K + k0 + c4) = o;
}

__global__ __launch_bounds__(256) void cvt_bias_kernel(
    const void* __restrict__ in, float* __restrict__ out, int n,
    const int* __restrict__ flag)
{
    int i = blockIdx.x * 256 + threadIdx.x;
    if (i < n)
        out[i] = (*flag) ? ((const float*)in)[i]
                         : __bfloat162float(((const bf16*)in)[i]);
}

// ---------------------------------------------------------------- embed
__global__ __launch_bounds__(256) void embed_kernel(
    const int* __restrict__ x, const void* __restrict__ tok,
    const void* __restrict__ pos, float* __restrict__ h,
    const int* __restrict__ flag)
{
    const int f32 = *flag;
    int row = blockIdx.x;           // b*1024 + t
    int t = row & 1023;
    int id = x[row];
    float* hp = h + (long)row * 1024;
    if (f32) {
        const float* tp = (const float*)tok + (long)id * 1024;
        const float* pp = (const float*)pos + (long)t * 1024;
        for (int c = threadIdx.x; c < 1024; c += 256)
            hp[c] = tp[c] + pp[c];
    } else {
        const bf16* tp = (const bf16*)tok + (long)id * 1024;
        const bf16* pp = (const bf16*)pos + (long)t * 1024;
        for (int c = threadIdx.x; c < 1024; c += 256)
            hp[c] = __bfloat162float(tp[c]) + __bfloat162float(pp[c]);
    }
}

// ---------------------------------------------------------------- layernorm
__global__ __launch_bounds__(256) void ln_kernel(
    const float* __restrict__ h, const void* __restrict__ g,
    const void* __restrict__ b, bf16* __restrict__ out,
    const int* __restrict__ flag)
{
    __shared__ float red[8];
    const int f32 = *flag;
    int row = blockIdx.x;
    const float* hp = h + (long)row * 1024;
    int t = threadIdx.x;
    float4 xv = ((const float4*)hp)[t];
    float s  = xv.x + xv.y + xv.z + xv.w;
    float ss = xv.x*xv.x + xv.y*xv.y + xv.z*xv.z + xv.w*xv.w;
    #pragma unroll
    for (int off = 32; off; off >>= 1) {
        s  += __shfl_down(s, off);
        ss += __shfl_down(ss, off);
    }
    int wv = t >> 6, lane = t & 63;
    if (lane == 0) { red[wv] = s; red[4 + wv] = ss; }
    __syncthreads();
    float fs  = red[0] + red[1] + red[2] + red[3];
    float fss = red[4] + red[5] + red[6] + red[7];
    float mu  = fs * (1.0f / 1024.0f);
    float var = fss * (1.0f / 1024.0f) - mu * mu;
    float rstd = rsqrtf(fmaxf(var, 0.f) + 1e-5f);
    bf16* op = out + (long)row * 1024;
    #pragma unroll
    for (int i = 0; i < 4; i++) {
        int c = t * 4 + i;
        float gv, bv_;
        if (f32) { gv = ((const float*)g)[c]; bv_ = ((const float*)b)[c]; }
        else     { gv = __bfloat162float(((const bf16*)g)[c]); bv_ = __bfloat162float(((const bf16*)b)[c]); }
        float xn = (((const float*)&xv)[i] - mu) * rstd;
        op[c] = __float2bfloat16(xn * gv + bv_);
    }
}

// ---------------------------------------------------------------- old generic GEMM
// kept only for the small Wo projection (K=64, N=64 per head).
template<bool RELU, bool RES_ADD, bool DYN_OUT>
__global__ __launch_bounds__(256) void gemm_kernel(
    const bf16* __restrict__ A, int lda, long a_bs,
    const void* __restrict__ B, int ldb, long b_bs,
    const void* __restrict__ bias, int bias_bs,
    void* __restrict__ Cv, int ldc, long c_bs, int K,
    const int* __restrict__ flag)
{
    __shared__ bf16 As[64][36];
    __shared__ bf16 Bs[64][36];   // stored transposed: Bs[n][k]
    const int f32 = *flag;
    const int tid = threadIdx.x;
    const int z = blockIdx.z;
    const bf16*  Ab   = A + (long)z * a_bs + (long)blockIdx.x * 64 * lda;
    const bf16*  Bb16 = (const bf16*)B  + (long)z * b_bs + (long)blockIdx.y * 64;
    const float* Bb32 = (const float*)B + (long)z * b_bs + (long)blockIdx.y * 64;
    const int wv = tid >> 6, lane = tid & 63, l16 = lane & 15, quad = lane >> 4;

    f32x4 acc[4];
    #pragma unroll
    for (int s = 0; s < 4; s++) { f32x4 z4 = {0.f,0.f,0.f,0.f}; acc[s] = z4; }

    const bool doA = tid < 128;
    const int ht = tid & 127;
    const int arow = ht >> 1;
    const int ak   = (ht & 1) * 16;
    const int bn   = (ht & 7) * 8;
    const int kp   = (ht >> 3) * 2;

    for (int k0 = 0; k0 < K; k0 += 32) {
        if (doA) {
            const bf16* src = Ab + (long)arow * lda + k0 + ak;
            V8 t0, t1;
            t0.v8 = *(const s16x8*)src;
            t1.v8 = *(const s16x8*)(src + 8);
            *(s16x4*)&As[arow][ak]      = t0.v4[0];
            *(s16x4*)&As[arow][ak + 4]  = t0.v4[1];
            *(s16x4*)&As[arow][ak + 8]  = t1.v4[0];
            *(s16x4*)&As[arow][ak + 12] = t1.v4[1];
        } else if (!f32) {
            const bf16* src = Bb16 + (long)(k0 + kp) * ldb + bn;
            s16x8 r0 = *(const s16x8*)src;
            s16x8 r1 = *(const s16x8*)(src + ldb);
            #pragma unroll
            for (int j = 0; j < 8; ++j) {
                unsigned int lo = (unsigned short)r0[j];
                unsigned int hi = (unsigned short)r1[j];
                *(unsigned int*)&Bs[bn + j][kp] = lo | (hi << 16);
            }
        } else {
            const float* src = Bb32 + (long)(k0 + kp) * ldb + bn;
            float4 a0 = *(const float4*)src;
            float4 a1 = *(const float4*)(src + 4);
            float4 c0 = *(const float4*)(src + ldb);
            float4 c1 = *(const float4*)(src + ldb + 4);
            float av[8] = {a0.x,a0.y,a0.z,a0.w,a1.x,a1.y,a1.z,a1.w};
            float cw[8] = {c0.x,c0.y,c0.z,c0.w,c1.x,c1.y,c1.z,c1.w};
            #pragma unroll
            for (int j = 0; j < 8; ++j) {
                unsigned int lo = f2bu(av[j]);
                unsigned int hi = f2bu(cw[j]);
                *(unsigned int*)&Bs[bn + j][kp] = lo | (hi << 16);
            }
        }
        __syncthreads();
        s16x8 af = ldfrag(&As[wv * 16 + l16][quad * 8]);
        #pragma unroll
        for (int s = 0; s < 4; ++s) {
            s16x8 bfr = ldfrag(&Bs[s * 16 + l16][quad * 8]);
            acc[s] = __builtin_amdgcn_mfma_f32_16x16x32_bf16(af, bfr, acc[s], 0, 0, 0);
        }
        __syncthreads();
    }

    const int gr0 = blockIdx.x * 64 + wv * 16 + quad * 4;
    const int gc0 = blockIdx.y * 64 + l16;
    #pragma unroll
    for (int s = 0; s < 4; ++s) {
        int gc = gc0 + s * 16;
        long bidx = (long)z * bias_bs + gc;
        float bv_ = f32 ? ((const float*)bias)[bidx]
                        : __bfloat162float(((const bf16*)bias)[bidx]);
        #pragma unroll
        for (int r = 0; r < 4; ++r) {
            long idx = (long)(gr0 + r) * ldc + gc;
            if (RES_ADD) {
                float* C = (float*)Cv + (long)z * c_bs;
                C[idx] += acc[s][r] + bv_;
            } else {
                float val = acc[s][r] + bv_;
                if (RELU) val = fmaxf(val, 0.f);
                if (DYN_OUT && f32)
                    ((float*)Cv)[(long)z * c_bs + idx] = val;
                else
                    ((bf16*)Cv)[(long)z * c_bs + idx] = __float2bfloat16(val);
            }
        }
    }
}

// ---------------------------------------------------------------- m97-style GEMM
// C[M,N] = A[M,K](bf16,row) @ Bt[N,K](bf16,row)^T + bias(f32).
// 128x128 tile, BK=32, 4 waves in 2x2, each wave 64x64 via 4x4 frags of 16x16x32.
// global_load_lds width-16 staging into linear LDS [128][32]; XCD-swizzled blockid.
template<bool RELU, bool RES_ADD, bool DYN_OUT>
__global__ __launch_bounds__(256) void gemm_bt_kernel(
    const bf16* __restrict__ A, int lda,
    const bf16* __restrict__ Bt,
    const float* __restrict__ bias,
    void* __restrict__ Cv, int ldc, int K,
    const int* __restrict__ flag)
{
    __shared__ bf16 As[4096];   // [128][32]
    __shared__ bf16 Bs[4096];   // [128][32]
    const int tid = threadIdx.x;
    const int wv = tid >> 6, lane = tid & 63, l16 = lane & 15, quad = lane >> 4;
    const int wr = wv >> 1, wc = wv & 1;

    // XCD-aware swizzle (all our grids have nwg % 8 == 0)
    const int gx = gridDim.x;
    int nwg = gx * gridDim.y;
    int lin = blockIdx.y * gx + blockIdx.x;
    int cpx = nwg >> 3;
    int swz = (lin & 7) * cpx + (lin >> 3);
    const int m0 = (swz % gx) * 128;
    const int n0 = (swz / gx) * 128;

    const int srow = lane >> 2;          // 0..15
    const int scol = (lane & 3) * 8;     // 0,8,16,24

    const bf16* Ap  = A  + (long)(m0 + wv * 16 + srow) * lda + scol;
    const bf16* Ap2 = A  + (long)(m0 + 64 + wv * 16 + srow) * lda + scol;
    const bf16* Bp  = Bt + (long)(n0 + wv * 16 + srow) * K + scol;
    const bf16* Bp2 = Bt + (long)(n0 + 64 + wv * 16 + srow) * K + scol;
    const bf16* lA  = &As[wv * 512];
    const bf16* lA2 = &As[2048 + wv * 512];
    const bf16* lB  = &Bs[wv * 512];
    const bf16* lB2 = &Bs[2048 + wv * 512];

    f32x4 acc[4][4];
    #pragma unroll
    for (int i = 0; i < 4; ++i)
        #pragma unroll
        for (int j = 0; j < 4; ++j) { f32x4 z4 = {0.f,0.f,0.f,0.f}; acc[i][j] = z4; }

    for (int k0 = 0; k0 < K; k0 += 32) {
        gload16(Ap  + k0, lA);
        gload16(Ap2 + k0, lA2);
        gload16(Bp  + k0, lB);
        gload16(Bp2 + k0, lB2);
        __syncthreads();
        s16x8 af[4], bfv[4];
        #pragma unroll
        for (int i = 0; i < 4; ++i)
            af[i] = *(const s16x8*)&As[(wr * 64 + i * 16 + l16) * 32 + quad * 8];
        #pragma unroll
        for (int j = 0; j < 4; ++j)
            bfv[j] = *(const s16x8*)&Bs[(wc * 64 + j * 16 + l16) * 32 + quad * 8];
        #pragma unroll
        for (int i = 0; i < 4; ++i)
            #pragma unroll
            for (int j = 0; j < 4; ++j)
                acc[i][j] = __builtin_amdgcn_mfma_f32_16x16x32_bf16(af[i], bfv[j], acc[i][j], 0, 0, 0);
        __syncthreads();
    }

    const int f32o = DYN_OUT ? *flag : 0;
    // C/D layout: col = l16, row = quad*4 + r
    #pragma unroll
    for (int j = 0; j < 4; ++j) {
        int col = n0 + wc * 64 + j * 16 + l16;
        float bv_ = bias[col];
        #pragma unroll
        for (int i = 0; i < 4; ++i) {
            int row = m0 + wr * 64 + i * 16 + quad * 4;
            #pragma unroll
            for (int r = 0; r < 4; ++r) {
                float val = acc[i][j][r] + bv_;
                long idx = (long)(row + r) * ldc + col;
                if (RES_ADD) {
                    ((float*)Cv)[idx] += val;
                } else if (DYN_OUT && f32o) {
                    ((float*)Cv)[idx] = val;
                } else {
                    if (RELU) val = fmaxf(val, 0.f);
                    ((bf16*)Cv)[idx] = __float2bfloat16(val);
                }
            }
        }
    }
}

// ---------------------------------------------------------------- flash attention
// qkv: [B*T][3072] fused (Q at col h*64, K at 1024+h*64, V at 2048+h*64).
// y:   [B*T][1024] (head h at col h*64).
__global__ __launch_bounds__(256) void flash_kernel(
    const bf16* __restrict__ qkv, bf16* __restrict__ y)
{
    __shared__ bf16 Qs[64][72];
    __shared__ bf16 Ks[64][72];
    __shared__ bf16 Vt[64][72];      // transposed: Vt[vdim][s]
    __shared__ bf16 Ps[4][16][72];   // per-wave P round-trip

    const int tid = threadIdx.x;
    const int wv = tid >> 6, lane = tid & 63, l16 = lane & 15, quad = lane >> 4;
    const int h = blockIdx.z >> 2, b = blockIdx.z & 3;
    const bf16* qp = qkv + (long)b * 1024 * 3072 + h * 64;
    const bf16* kp = qp + 1024;
    const bf16* vp = qp + 2048;
    const int q0 = blockIdx.x * 64;

    {
        int row = tid >> 2, c0 = (tid & 3) * 16;
        const bf16* src = qp + (long)(q0 + row) * 3072 + c0;
        *(s16x8*)&Qs[row][c0]     = *(const s16x8*)src;
        *(s16x8*)&Qs[row][c0 + 8] = *(const s16x8*)(src + 8);
    }
    __syncthreads();
    s16x8 qa0 = *(const s16x8*)&Qs[wv * 16 + l16][quad * 8];
    s16x8 qa1 = *(const s16x8*)&Qs[wv * 16 + l16][32 + quad * 8];

    float m_i[4] = {NEG_INF, NEG_INF, NEG_INF, NEG_INF};
    float l_i[4] = {0.f, 0.f, 0.f, 0.f};
    f32x4 o[4];
    #pragma unroll
    for (int s = 0; s < 4; s++) { f32x4 z4 = {0.f,0.f,0.f,0.f}; o[s] = z4; }
    const int qrow_w = q0 + wv * 16 + quad * 4;

    const int nst = blockIdx.x + 1;
    for (int st = 0; st < nst; ++st) {
        const int s0 = st * 64;
        __syncthreads();
        {
            int row = tid >> 2, c0 = (tid & 3) * 16;
            const bf16* src = kp + (long)(s0 + row) * 3072 + c0;
            *(s16x8*)&Ks[row][c0]     = *(const s16x8*)src;
            *(s16x8*)&Ks[row][c0 + 8] = *(const s16x8*)(src + 8);
            int c0v = (tid & 7) * 8, sp = (tid >> 3) * 2;
            const bf16* vsrc = vp + (long)(s0 + sp) * 3072 + c0v;
            s16x8 vlo = *(const s16x8*)vsrc;
            s16x8 vhi = *(const s16x8*)(vsrc + 3072);
            #pragma unroll
            for (int j = 0; j < 8; ++j) {
                unsigned int lo = (unsigned short)vlo[j];
                unsigned int hi = (unsigned short)vhi[j];
                *(unsigned int*)&Vt[c0v + j][sp] = lo | (hi << 16);
            }
        }
        __syncthreads();

        f32x4 S[4];
        #pragma unroll
        for (int s = 0; s < 4; ++s) {
            f32x4 z4 = {0.f,0.f,0.f,0.f};
            s16x8 kb0 = *(const s16x8*)&Ks[s * 16 + l16][quad * 8];
            s16x8 kb1 = *(const s16x8*)&Ks[s * 16 + l16][32 + quad * 8];
            z4 = __builtin_amdgcn_mfma_f32_16x16x32_bf16(qa0, kb0, z4, 0, 0, 0);
            z4 = __builtin_amdgcn_mfma_f32_16x16x32_bf16(qa1, kb1, z4, 0, 0, 0);
            S[s] = z4;
        }
        #pragma unroll
        for (int s = 0; s < 4; ++s) {
            int sg = s0 + s * 16 + l16;
            #pragma unroll
            for (int r = 0; r < 4; ++r) {
                float val = S[s][r] * 0.125f;
                if (sg > qrow_w + r) val = NEG_INF;
                S[s][r] = val;
            }
        }
        float alpha[4];
        #pragma unroll
        for (int r = 0; r < 4; ++r) {
            float mx = fmaxf(fmaxf(S[0][r], S[1][r]), fmaxf(S[2][r], S[3][r]));
            #pragma unroll
            for (int off = 1; off < 16; off <<= 1)
                mx = fmaxf(mx, __shfl_xor(mx, off));
            float mnew = fmaxf(m_i[r], mx);
            alpha[r] = __expf(fmaxf(m_i[r] - mnew, -80.f));
            m_i[r] = mnew;
        }
        float rs[4] = {0.f, 0.f, 0.f, 0.f};
        #pragma unroll
        for (int s = 0; s < 4; ++s)
            #pragma unroll
            for (int r = 0; r < 4; ++r) {
                float p = __expf(fmaxf(S[s][r] - m_i[r], -80.f));
                S[s][r] = p;
                rs[r] += p;
            }
        #pragma unroll
        for (int r = 0; r < 4; ++r) {
            #pragma unroll
            for (int off = 1; off < 16; off <<= 1)
                rs[r] += __shfl_xor(rs[r], off);
            l_i[r] = l_i[r] * alpha[r] + rs[r];
        }
        #pragma unroll
        for (int s = 0; s < 4; ++s)
            #pragma unroll
            for (int r = 0; r < 4; ++r)
                Ps[wv][quad * 4 + r][s * 16 + l16] = __float2bfloat16(S[s][r]);
        __syncthreads();   // defensive: order Ps stores before vector reload
        s16x8 pa0 = *(const s16x8*)&Ps[wv][l16][quad * 8];
        s16x8 pa1 = *(const s16x8*)&Ps[wv][l16][32 + quad * 8];
        #pragma unroll
        for (int s = 0; s < 4; ++s) {
            #pragma unroll
            for (int r = 0; r < 4; ++r) o[s][r] *= alpha[r];
            s16x8 vb0 = *(const s16x8*)&Vt[s * 16 + l16][quad * 8];
            s16x8 vb1 = *(const s16x8*)&Vt[s * 16 + l16][32 + quad * 8];
            o[s] = __builtin_amdgcn_mfma_f32_16x16x32_bf16(pa0, vb0, o[s], 0, 0, 0);
            o[s] = __builtin_amdgcn_mfma_f32_16x16x32_bf16(pa1, vb1, o[s], 0, 0, 0);
        }
    }
    float inv[4];
    #pragma unroll
    for (int r = 0; r < 4; ++r) inv[r] = 1.0f / l_i[r];
    bf16* yp = y + (long)b * 1024 * 1024 + h * 64;
    #pragma unroll
    for (int s = 0; s < 4; ++s)
        #pragma unroll
        for (int r = 0; r < 4; ++r)
            yp[(long)(qrow_w + r) * 1024 + s * 16 + l16] = __float2bfloat16(o[s][r] * inv[r]);
}

// ---------------------------------------------------------------- launch
extern "C" void kernel_launch(void* const* d_in, const int* in_sizes, int n_in,
                              void* d_out, int out_size, void* d_ws, size_t ws_size,
                              hipStream_t stream)
{
    const int*  x    = (const int*)d_in[0];
    const void* tok  = d_in[1];
    const void* pos  = d_in[2];
    const void* Wq   = d_in[3];
    const void* bq   = d_in[4];
    const void* Wk   = d_in[5];
    const void* bk_  = d_in[6];
    const void* Wv   = d_in[7];
    const void* bv   = d_in[8];
    const void* Wo   = d_in[9];
    const void* bo   = d_in[10];
    const void* W1   = d_in[11];
    const void* b1   = d_in[12];
    const void* W2   = d_in[13];
    const void* b2   = d_in[14];
    const void* ln1g = d_in[15];
    const void* ln1b = d_in[16];
    const void* ln2g = d_in[17];
    const void* ln2b = d_in[18];
    const void* lnfg = d_in[19];
    const void* lnfb = d_in[20];
    const void* Wout = d_in[21];
    const void* bout = d_in[22];

    char* w = (char*)d_ws;
    int* flagp = (int*)w;        w += 256;
    float* h   = (float*)w;      w += 4096L * 1024 * 4;   // residual stream fp32
    bf16* xn   = (bf16*)w;       w += 4096L * 1024 * 2;   // LN output (reused)
    bf16* qkvb = (bf16*)w;       w += 4096L * 3072 * 2;   // fused QKV activations
    bf16* yb   = (bf16*)w;       w += 4096L * 1024 * 2;   // attention output
    bf16* mid  = (bf16*)w;       w += 4096L * 4096 * 2;   // FF intermediate
    bf16* WqkvT = (bf16*)w;      w += 3072L * 1024 * 2;   // [3072][1024] bf16
    bf16* W1T  = (bf16*)w;       w += 4096L * 1024 * 2;   // [4096][1024]
    bf16* W2T  = (bf16*)w;       w += 1024L * 4096 * 2;   // [1024][4096]
    bf16* WoutT = (bf16*)w;      w += 32000L * 1024 * 2;  // [32000][1024]
    float* bqkvf = (float*)w;    w += 3072L * 4;
    float* b1f  = (float*)w;     w += 4096L * 4;
    float* b2f  = (float*)w;     w += 1024L * 4;
    float* boutf = (float*)w;    w += 32000L * 4;

    sniff_kernel<<<1, 64, 0, stream>>>((const unsigned short*)tok, flagp);

    // one-time weight prep (weights are tied across layers -> reused 4x)
    transpose_cvt_kernel<<<dim3(2, 32, 16), 256, 0, stream>>>(
        Wq, WqkvT, 64, 1024, 65536, 65536, flagp);
    transpose_cvt_kernel<<<dim3(2, 32, 16), 256, 0, stream>>>(
        Wk, WqkvT + 1024L * 1024, 64, 1024, 65536, 65536, flagp);
    transpose_cvt_kernel<<<dim3(2, 32, 16), 256, 0, stream>>>(
        Wv, WqkvT + 2048L * 1024, 64, 1024, 65536, 65536, flagp);
    transpose_cvt_kernel<<<dim3(128, 32, 1), 256, 0, stream>>>(
        W1, W1T, 4096, 1024, 0, 0, flagp);
    transpose_cvt_kernel<<<dim3(32, 128, 1), 256, 0, stream>>>(
        W2, W2T, 1024, 4096, 0, 0, flagp);
    transpose_cvt_kernel<<<dim3(1000, 32, 1), 256, 0, stream>>>(
        Wout, WoutT, 32000, 1024, 0, 0, flagp);
    cvt_bias_kernel<<<4, 256, 0, stream>>>(bq, bqkvf, 1024, flagp);
    cvt_bias_kernel<<<4, 256, 0, stream>>>(bk_, bqkvf + 1024, 1024, flagp);
    cvt_bias_kernel<<<4, 256, 0, stream>>>(bv, bqkvf + 2048, 1024, flagp);
    cvt_bias_kernel<<<16, 256, 0, stream>>>(b1, b1f, 4096, flagp);
    cvt_bias_kernel<<<4, 256, 0, stream>>>(b2, b2f, 1024, flagp);
    cvt_bias_kernel<<<125, 256, 0, stream>>>(bout, boutf, 32000, flagp);

    embed_kernel<<<4096, 256, 0, stream>>>(x, tok, pos, h, flagp);

    for (int layer = 0; layer < 4; ++layer) {
        ln_kernel<<<4096, 256, 0, stream>>>(h, ln1g, ln1b, xn, flagp);
        // fused QKV: [4096,1024] @ [1024,3072] -> [4096,3072]
        gemm_bt_kernel<false,false,false><<<dim3(32, 24), 256, 0, stream>>>(
            xn, 1024, WqkvT, bqkvf, qkvb, 3072, 1024, flagp);
        flash_kernel<<<dim3(16, 1, 64), 256, 0, stream>>>(qkvb, yb);
        // per-head output projection + residual add (old kernel; K=64 tiny)
        gemm_kernel<false,true,false><<<dim3(64, 1, 16), 256, 0, stream>>>(
            yb, 1024, 64, Wo, 64, 4096, bo, 64, h, 1024, 64, 64, flagp);
        ln_kernel<<<4096, 256, 0, stream>>>(h, ln2g, ln2b, xn, flagp);
        gemm_bt_kernel<true,false,false><<<dim3(32, 32), 256, 0, stream>>>(
            xn, 1024, W1T, b1f, mid, 4096, 1024, flagp);
        gemm_bt_kernel<false,true,false><<<dim3(32, 8), 256, 0, stream>>>(
            mid, 4096, W2T, b2f, h, 1024, 4096, flagp);
    }

    ln_kernel<<<4096, 256, 0, stream>>>(h, lnfg, lnfb, xn, flagp);
    gemm_bt_kernel<false,false,true><<<dim3(32, 250), 256, 0, stream>>>(
        xn, 1024, WoutT, boutf, d_out, 32000, 1024, flagp);
}

// Round 2
// 2424.437 us; speedup vs baseline: 1.2904x; 1.0789x over previous
//
#include <hip/hip_runtime.h>
#include <hip/hip_bf16.h>

typedef __hip_bfloat16 bf16;
typedef __attribute__((ext_vector_type(8))) short s16x8;
typedef __attribute__((ext_vector_type(4))) short s16x4;
typedef __attribute__((ext_vector_type(4))) float f32x4;

#define NEG_INF (-__builtin_inff())

union V8 { s16x8 v8; s16x4 v4[2]; };

__device__ inline unsigned short f2bu(float f) {
    union { bf16 b; unsigned short u; } c;
    c.b = __float2bfloat16(f);
    return c.u;
}

__device__ inline float bu2f(unsigned short u) {
    union { bf16 b; unsigned short u; } c;
    c.u = u;
    return __bfloat162float(c.b);
}

// global -> LDS direct copy, 16B per lane. LDS dest is wave-uniform base;
// HW writes lane i at base + i*16. Global source address is per-lane.
__device__ inline void gload16(const bf16* gsrc, const bf16* ldst) {
    __builtin_amdgcn_global_load_lds(
        (const __attribute__((address_space(1))) unsigned int*)(unsigned long long)gsrc,
        (__attribute__((address_space(3))) unsigned int*)(unsigned int)(unsigned long long)ldst,
        16, 0, 0);
}

// ---------------------------------------------------------------- dtype sniff
__global__ void sniff_kernel(const unsigned short* __restrict__ tok, int* __restrict__ flag)
{
    int big = 0;
    for (int i = threadIdx.x; i < 2048; i += 64) {
        unsigned e = (tok[i] >> 7) & 0xFFu;
        if (e >= 127u) big++;
    }
    #pragma unroll
    for (int off = 32; off; off >>= 1) big += __shfl_down(big, off);
    if (threadIdx.x == 0) *flag = (big > 64) ? 1 : 0;
}

// ---------------------------------------------------------------- weight prep
// out[N][K] bf16 = transpose(in[K][N]) with fp32-or-bf16 input. 32x32 tiles.
__global__ __launch_bounds__(256) void transpose_cvt_kernel(
    const void* __restrict__ in, bf16* __restrict__ out,
    int N, int K, long in_bs, long out_bs, const int* __restrict__ flag)
{
    __shared__ float tile[32][33];
    const int f32 = *flag;
    const int z = blockIdx.z;
    const int n0 = blockIdx.x * 32, k0 = blockIdx.y * 32;
    const int r  = threadIdx.x >> 3;
    const int c4 = (threadIdx.x & 7) * 4;
    if (f32) {
        const float* ip = (const float*)in + z * in_bs;
        float4 v = *(const float4*)(ip + (long)(k0 + r) * N + n0 + c4);
        tile[r][c4 + 0] = v.x; tile[r][c4 + 1] = v.y;
        tile[r][c4 + 2] = v.z; tile[r][c4 + 3] = v.w;
    } else {
        const bf16* ip = (const bf16*)in + z * in_bs;
        ushort4 v = *(const ushort4*)(ip + (long)(k0 + r) * N + n0 + c4);
        tile[r][c4 + 0] = bu2f(v.x); tile[r][c4 + 1] = bu2f(v.y);
        tile[r][c4 + 2] = bu2f(v.z); tile[r][c4 + 3] = bu2f(v.w);
    }
    __syncthreads();
    bf16* op = out + z * out_bs;
    ushort4 o;
    o.x = f2bu(tile[c4 + 0][r]); o.y = f2bu(tile[c4 + 1][r]);
    o.z = f2bu(tile[c4 + 2][r]); o.w = f2bu(tile[c4 + 3][r]);
    *(ushort4*)(op + (long)(n0 + r) * K + k0 + c4) = o;
}

__global__ __launch_bounds__(256) void cvt_bias_kernel(
    const void* __restrict__ in, float* __restrict__ out, int n,
    const int* __restrict__ flag)
{
    int i = blockIdx.x * 256 + threadIdx.x;
    if (i < n)
        out[i] = (*flag) ? ((const float*)in)[i]
                         : __bfloat162float(((const bf16*)in)[i]);
}

// Dense block-diagonal Wo: WoT[n][k] (n = h*64+o, k = h2*64+v) =
//   (h==h2) ? Wo[h][v][o] : 0.   [1024][1024] bf16, Bt layout for gemm_bt.
__global__ __launch_bounds__(256) void prep_wo_kernel(
    const void* __restrict__ Wo, bf16* __restrict__ WoT, const int* __restrict__ flag)
{
    const int f32 = *flag;
    int idx = blockIdx.x * 256 + threadIdx.x;   // n*1024 + k
    int n = idx >> 10, k = idx & 1023;
    int h = n >> 6, o = n & 63, h2 = k >> 6, v = k & 63;
    float val = 0.f;
    if (h == h2) {
        long widx = ((long)h * 64 + v) * 64 + o;
        val = f32 ? ((const float*)Wo)[widx]
                  : __bfloat162float(((const bf16*)Wo)[widx]);
    }
    WoT[idx] = __float2bfloat16(val);
}

// ---------------------------------------------------------------- embed
__global__ __launch_bounds__(256) void embed_kernel(
    const int* __restrict__ x, const void* __restrict__ tok,
    const void* __restrict__ pos, float* __restrict__ h,
    const int* __restrict__ flag)
{
    const int f32 = *flag;
    int row = blockIdx.x;           // b*1024 + t
    int t = row & 1023;
    int id = x[row];
    float* hp = h + (long)row * 1024;
    if (f32) {
        const float* tp = (const float*)tok + (long)id * 1024;
        const float* pp = (const float*)pos + (long)t * 1024;
        for (int c = threadIdx.x; c < 1024; c += 256)
            hp[c] = tp[c] + pp[c];
    } else {
        const bf16* tp = (const bf16*)tok + (long)id * 1024;
        const bf16* pp = (const bf16*)pos + (long)t * 1024;
        for (int c = threadIdx.x; c < 1024; c += 256)
            hp[c] = __bfloat162float(tp[c]) + __bfloat162float(pp[c]);
    }
}

// ---------------------------------------------------------------- layernorm
__global__ __launch_bounds__(256) void ln_kernel(
    const float* __restrict__ h, const void* __restrict__ g,
    const void* __restrict__ b, bf16* __restrict__ out,
    const int* __restrict__ flag)
{
    __shared__ float red[8];
    const int f32 = *flag;
    int row = blockIdx.x;
    const float* hp = h + (long)row * 1024;
    int t = threadIdx.x;
    float4 xv = ((const float4*)hp)[t];
    float s  = xv.x + xv.y + xv.z + xv.w;
    float ss = xv.x*xv.x + xv.y*xv.y + xv.z*xv.z + xv.w*xv.w;
    #pragma unroll
    for (int off = 32; off; off >>= 1) {
        s  += __shfl_down(s, off);
        ss += __shfl_down(ss, off);
    }
    int wv = t >> 6, lane = t & 63;
    if (lane == 0) { red[wv] = s; red[4 + wv] = ss; }
    __syncthreads();
    float fs  = red[0] + red[1] + red[2] + red[3];
    float fss = red[4] + red[5] + red[6] + red[7];
    float mu  = fs * (1.0f / 1024.0f);
    float var = fss * (1.0f / 1024.0f) - mu * mu;
    float rstd = rsqrtf(fmaxf(var, 0.f) + 1e-5f);
    bf16* op = out + (long)row * 1024;
    #pragma unroll
    for (int i = 0; i < 4; i++) {
        int c = t * 4 + i;
        float gv, bv_;
        if (f32) { gv = ((const float*)g)[c]; bv_ = ((const float*)b)[c]; }
        else     { gv = __bfloat162float(((const bf16*)g)[c]); bv_ = __bfloat162float(((const bf16*)b)[c]); }
        float xn = (((const float*)&xv)[i] - mu) * rstd;
        op[c] = __float2bfloat16(xn * gv + bv_);
    }
}

// ---------------------------------------------------------------- GEMM helpers
// Stage one 128x32 K-tile pair (A and B halves) into LDS buffers.
__device__ __forceinline__ void gemm_stage(
    const bf16* Ap, const bf16* Ap2, const bf16* Bp, const bf16* Bp2,
    bf16* asb, bf16* bsb, int wv, int koff)
{
    gload16(Ap + koff,  asb + wv * 512);
    gload16(Ap2 + koff, asb + 2048 + wv * 512);
    gload16(Bp + koff,  bsb + wv * 512);
    gload16(Bp2 + koff, bsb + 2048 + wv * 512);
}

// Read fragments (bank-conflict-swizzled) and accumulate 4x4 MFMAs.
__device__ __forceinline__ void gemm_compute(
    const bf16* __restrict__ asb, const bf16* __restrict__ bsb,
    int wr, int wc, int l16, int rchunk, f32x4 (&acc)[4][4])
{
    s16x8 af[4], bfv[4];
    #pragma unroll
    for (int i = 0; i < 4; ++i)
        af[i] = *(const s16x8*)&asb[(wr * 64 + i * 16 + l16) * 32 + rchunk];
    #pragma unroll
    for (int j = 0; j < 4; ++j)
        bfv[j] = *(const s16x8*)&bsb[(wc * 64 + j * 16 + l16) * 32 + rchunk];
    #pragma unroll
    for (int i = 0; i < 4; ++i)
        #pragma unroll
        for (int j = 0; j < 4; ++j)
            acc[i][j] = __builtin_amdgcn_mfma_f32_16x16x32_bf16(af[i], bfv[j], acc[i][j], 0, 0, 0);
}

// ---------------------------------------------------------------- 2-phase GEMM
// C[M,N] = A[M,K](bf16,row) @ Bt[N,K](bf16,row)^T + bias(f32).
// 128x128 tile, BK=32, double-buffered LDS, prefetch-next-while-compute,
// one barrier per K-step (implicit vmcnt(0) lands the prefetch).
// Chunk swizzle: LDS row r chunk c holds global chunk c^((r>>1)&3) —
// applied on BOTH global source (gload_lds writes linearly) and ds_read.
// Requires K % 64 == 0.
template<bool RELU, bool RES_ADD, bool DYN_OUT>
__global__ __launch_bounds__(256) void gemm_bt_kernel(
    const bf16* __restrict__ A, int lda,
    const bf16* __restrict__ Bt,
    const float* __restrict__ bias,
    void* __restrict__ Cv, int ldc, int K,
    const int* __restrict__ flag)
{
    __shared__ bf16 As[2][4096];   // [buf][128 rows][32 cols]
    __shared__ bf16 Bs[2][4096];
    const int tid = threadIdx.x;
    const int wv = tid >> 6, lane = tid & 63, l16 = lane & 15, quad = lane >> 4;
    const int wr = wv >> 1, wc = wv & 1;

    // XCD-aware swizzle (all grids have nwg % 8 == 0)
    const int gx = gridDim.x;
    int nwg = gx * gridDim.y;
    int lin = blockIdx.y * gx + blockIdx.x;
    int cpx = nwg >> 3;
    int swz = (lin & 7) * cpx + (lin >> 3);
    const int m0 = (swz % gx) * 128;
    const int n0 = (swz / gx) * 128;

    const int srow = lane >> 2;                                  // 0..15
    const int scol = ((lane & 3) ^ ((lane >> 3) & 3)) * 8;       // pre-swizzled chunk
    const int rchunk = (quad ^ ((l16 >> 1) & 3)) * 8;            // ds_read chunk

    const bf16* Ap  = A  + (long)(m0 + wv * 16 + srow) * lda + scol;
    const bf16* Ap2 = A  + (long)(m0 + 64 + wv * 16 + srow) * lda + scol;
    const bf16* Bp  = Bt + (long)(n0 + wv * 16 + srow) * K + scol;
    const bf16* Bp2 = Bt + (long)(n0 + 64 + wv * 16 + srow) * K + scol;

    f32x4 acc[4][4];
    #pragma unroll
    for (int i = 0; i < 4; ++i)
        #pragma unroll
        for (int j = 0; j < 4; ++j) { f32x4 z4 = {0.f,0.f,0.f,0.f}; acc[i][j] = z4; }

    gemm_stage(Ap, Ap2, Bp, Bp2, As[0], Bs[0], wv, 0);
    __syncthreads();

    for (int k0 = 0; k0 < K; k0 += 64) {
        // phase A: prefetch tile (k0+32) -> buf1, compute buf0 (tile k0)
        if (k0 + 32 < K)
            gemm_stage(Ap, Ap2, Bp, Bp2, As[1], Bs[1], wv, k0 + 32);
        gemm_compute(As[0], Bs[0], wr, wc, l16, rchunk, acc);
        __syncthreads();   // drains own gloads (vmcnt 0) + orders buf reuse
        // phase B: prefetch tile (k0+64) -> buf0, compute buf1 (tile k0+32)
        if (k0 + 64 < K)
            gemm_stage(Ap, Ap2, Bp, Bp2, As[0], Bs[0], wv, k0 + 64);
        gemm_compute(As[1], Bs[1], wr, wc, l16, rchunk, acc);
        __syncthreads();
    }

    const int f32o = DYN_OUT ? *flag : 0;
    // C/D layout: col = l16, row = quad*4 + r
    #pragma unroll
    for (int j = 0; j < 4; ++j) {
        int col = n0 + wc * 64 + j * 16 + l16;
        float bv_ = bias[col];
        #pragma unroll
        for (int i = 0; i < 4; ++i) {
            int row = m0 + wr * 64 + i * 16 + quad * 4;
            #pragma unroll
            for (int r = 0; r < 4; ++r) {
                float val = acc[i][j][r] + bv_;
                long idx = (long)(row + r) * ldc + col;
                if (RES_ADD) {
                    ((float*)Cv)[idx] += val;
                } else if (DYN_OUT && f32o) {
                    ((float*)Cv)[idx] = val;
                } else {
                    if (RELU) val = fmaxf(val, 0.f);
                    ((bf16*)Cv)[idx] = __float2bfloat16(val);
                }
            }
        }
    }
}

// ---------------------------------------------------------------- flash attention
// qkv: [B*T][3072] fused (Q at col h*64, K at 1024+h*64, V at 2048+h*64).
// y:   [B*T][1024] (head h at col h*64).
__global__ __launch_bounds__(256) void flash_kernel(
    const bf16* __restrict__ qkv, bf16* __restrict__ y)
{
    __shared__ bf16 Qs[64][72];
    __shared__ bf16 Ks[64][72];
    __shared__ bf16 Vt[64][72];      // transposed: Vt[vdim][s]
    __shared__ bf16 Ps[4][16][72];   // per-wave P round-trip

    const int tid = threadIdx.x;
    const int wv = tid >> 6, lane = tid & 63, l16 = lane & 15, quad = lane >> 4;
    const int h = blockIdx.z >> 2, b = blockIdx.z & 3;
    const bf16* qp = qkv + (long)b * 1024 * 3072 + h * 64;
    const bf16* kp = qp + 1024;
    const bf16* vp = qp + 2048;
    const int q0 = blockIdx.x * 64;

    {
        int row = tid >> 2, c0 = (tid & 3) * 16;
        const bf16* src = qp + (long)(q0 + row) * 3072 + c0;
        *(s16x8*)&Qs[row][c0]     = *(const s16x8*)src;
        *(s16x8*)&Qs[row][c0 + 8] = *(const s16x8*)(src + 8);
    }
    __syncthreads();
    s16x8 qa0 = *(const s16x8*)&Qs[wv * 16 + l16][quad * 8];
    s16x8 qa1 = *(const s16x8*)&Qs[wv * 16 + l16][32 + quad * 8];

    float m_i[4] = {NEG_INF, NEG_INF, NEG_INF, NEG_INF};
    float l_i[4] = {0.f, 0.f, 0.f, 0.f};
    f32x4 o[4];
    #pragma unroll
    for (int s = 0; s < 4; s++) { f32x4 z4 = {0.f,0.f,0.f,0.f}; o[s] = z4; }
    const int qrow_w = q0 + wv * 16 + quad * 4;

    const int nst = blockIdx.x + 1;
    for (int st = 0; st < nst; ++st) {
        const int s0 = st * 64;
        __syncthreads();
        {
            int row = tid >> 2, c0 = (tid & 3) * 16;
            const bf16* src = kp + (long)(s0 + row) * 3072 + c0;
            *(s16x8*)&Ks[row][c0]     = *(const s16x8*)src;
            *(s16x8*)&Ks[row][c0 + 8] = *(const s16x8*)(src + 8);
            int c0v = (tid & 7) * 8, sp = (tid >> 3) * 2;
            const bf16* vsrc = vp + (long)(s0 + sp) * 3072 + c0v;
            s16x8 vlo = *(const s16x8*)vsrc;
            s16x8 vhi = *(const s16x8*)(vsrc + 3072);
            #pragma unroll
            for (int j = 0; j < 8; ++j) {
                unsigned int lo = (unsigned short)vlo[j];
                unsigned int hi = (unsigned short)vhi[j];
                *(unsigned int*)&Vt[c0v + j][sp] = lo | (hi << 16);
            }
        }
        __syncthreads();

        f32x4 S[4];
        #pragma unroll
        for (int s = 0; s < 4; ++s) {
            f32x4 z4 = {0.f,0.f,0.f,0.f};
            s16x8 kb0 = *(const s16x8*)&Ks[s * 16 + l16][quad * 8];
            s16x8 kb1 = *(const s16x8*)&Ks[s * 16 + l16][32 + quad * 8];
            z4 = __builtin_amdgcn_mfma_f32_16x16x32_bf16(qa0, kb0, z4, 0, 0, 0);
            z4 = __builtin_amdgcn_mfma_f32_16x16x32_bf16(qa1, kb1, z4, 0, 0, 0);
            S[s] = z4;
        }
        #pragma unroll
        for (int s = 0; s < 4; ++s) {
            int sg = s0 + s * 16 + l16;
            #pragma unroll
            for (int r = 0; r < 4; ++r) {
                float val = S[s][r] * 0.125f;
                if (sg > qrow_w + r) val = NEG_INF;
                S[s][r] = val;
            }
        }
        float alpha[4];
        #pragma unroll
        for (int r = 0; r < 4; ++r) {
            float mx = fmaxf(fmaxf(S[0][r], S[1][r]), fmaxf(S[2][r], S[3][r]));
            #pragma unroll
            for (int off = 1; off < 16; off <<= 1)
                mx = fmaxf(mx, __shfl_xor(mx, off));
            float mnew = fmaxf(m_i[r], mx);
            alpha[r] = __expf(fmaxf(m_i[r] - mnew, -80.f));
            m_i[r] = mnew;
        }
        float rs[4] = {0.f, 0.f, 0.f, 0.f};
        #pragma unroll
        for (int s = 0; s < 4; ++s)
            #pragma unroll
            for (int r = 0; r < 4; ++r) {
                float p = __expf(fmaxf(S[s][r] - m_i[r], -80.f));
                S[s][r] = p;
                rs[r] += p;
            }
        #pragma unroll
        for (int r = 0; r < 4; ++r) {
            #pragma unroll
            for (int off = 1; off < 16; off <<= 1)
                rs[r] += __shfl_xor(rs[r], off);
            l_i[r] = l_i[r] * alpha[r] + rs[r];
        }
        #pragma unroll
        for (int s = 0; s < 4; ++s)
            #pragma unroll
            for (int r = 0; r < 4; ++r)
                Ps[wv][quad * 4 + r][s * 16 + l16] = __float2bfloat16(S[s][r]);
        __syncthreads();   // defensive: order Ps stores before vector reload
        s16x8 pa0 = *(const s16x8*)&Ps[wv][l16][quad * 8];
        s16x8 pa1 = *(const s16x8*)&Ps[wv][l16][32 + quad * 8];
        #pragma unroll
        for (int s = 0; s < 4; ++s) {
            #pragma unroll
            for (int r = 0; r < 4; ++r) o[s][r] *= alpha[r];
            s16x8 vb0 = *(const s16x8*)&Vt[s * 16 + l16][quad * 8];
            s16x8 vb1 = *(const s16x8*)&Vt[s * 16 + l16][32 + quad * 8];
            o[s] = __builtin_amdgcn_mfma_f32_16x16x32_bf16(pa0, vb0, o[s], 0, 0, 0);
            o[s] = __builtin_amdgcn_mfma_f32_16x16x32_bf16(pa1, vb1, o[s], 0, 0, 0);
        }
    }
    float inv[4];
    #pragma unroll
    for (int r = 0; r < 4; ++r) inv[r] = 1.0f / l_i[r];
    bf16* yp = y + (long)b * 1024 * 1024 + h * 64;
    #pragma unroll
    for (int s = 0; s < 4; ++s)
        #pragma unroll
        for (int r = 0; r < 4; ++r)
            yp[(long)(qrow_w + r) * 1024 + s * 16 + l16] = __float2bfloat16(o[s][r] * inv[r]);
}

// ---------------------------------------------------------------- launch
extern "C" void kernel_launch(void* const* d_in, const int* in_sizes, int n_in,
                              void* d_out, int out_size, void* d_ws, size_t ws_size,
                              hipStream_t stream)
{
    const int*  x    = (const int*)d_in[0];
    const void* tok  = d_in[1];
    const void* pos  = d_in[2];
    const void* Wq   = d_in[3];
    const void* bq   = d_in[4];
    const void* Wk   = d_in[5];
    const void* bk_  = d_in[6];
    const void* Wv   = d_in[7];
    const void* bv   = d_in[8];
    const void* Wo   = d_in[9];
    const void* bo   = d_in[10];
    const void* W1   = d_in[11];
    const void* b1   = d_in[12];
    const void* W2   = d_in[13];
    const void* b2   = d_in[14];
    const void* ln1g = d_in[15];
    const void* ln1b = d_in[16];
    const void* ln2g = d_in[17];
    const void* ln2b = d_in[18];
    const void* lnfg = d_in[19];
    const void* lnfb = d_in[20];
    const void* Wout = d_in[21];
    const void* bout = d_in[22];

    char* w = (char*)d_ws;
    int* flagp = (int*)w;        w += 256;
    float* h   = (float*)w;      w += 4096L * 1024 * 4;   // residual stream fp32
    bf16* xn   = (bf16*)w;       w += 4096L * 1024 * 2;   // LN output (reused)
    bf16* qkvb = (bf16*)w;       w += 4096L * 3072 * 2;   // fused QKV activations
    bf16* yb   = (bf16*)w;       w += 4096L * 1024 * 2;   // attention output
    bf16* mid  = (bf16*)w;       w += 4096L * 4096 * 2;   // FF intermediate
    bf16* WqkvT = (bf16*)w;      w += 3072L * 1024 * 2;   // [3072][1024] bf16
    bf16* W1T  = (bf16*)w;       w += 4096L * 1024 * 2;   // [4096][1024]
    bf16* W2T  = (bf16*)w;       w += 1024L * 4096 * 2;   // [1024][4096]
    bf16* WoutT = (bf16*)w;      w += 32000L * 1024 * 2;  // [32000][1024]
    bf16* WoT  = (bf16*)w;       w += 1024L * 1024 * 2;   // dense block-diag Wo
    float* bqkvf = (float*)w;    w += 3072L * 4;
    float* b1f  = (float*)w;     w += 4096L * 4;
    float* b2f  = (float*)w;     w += 1024L * 4;
    float* bof  = (float*)w;     w += 1024L * 4;
    float* boutf = (float*)w;    w += 32000L * 4;

    sniff_kernel<<<1, 64, 0, stream>>>((const unsigned short*)tok, flagp);

    // one-time weight prep (weights are tied across layers -> reused 4x)
    transpose_cvt_kernel<<<dim3(2, 32, 16), 256, 0, stream>>>(
        Wq, WqkvT, 64, 1024, 65536, 65536, flagp);
    transpose_cvt_kernel<<<dim3(2, 32, 16), 256, 0, stream>>>(
        Wk, WqkvT + 1024L * 1024, 64, 1024, 65536, 65536, flagp);
    transpose_cvt_kernel<<<dim3(2, 32, 16), 256, 0, stream>>>(
        Wv, WqkvT + 2048L * 1024, 64, 1024, 65536, 65536, flagp);
    transpose_cvt_kernel<<<dim3(128, 32, 1), 256, 0, stream>>>(
        W1, W1T, 4096, 1024, 0, 0, flagp);
    transpose_cvt_kernel<<<dim3(32, 128, 1), 256, 0, stream>>>(
        W2, W2T, 1024, 4096, 0, 0, flagp);
    transpose_cvt_kernel<<<dim3(1000, 32, 1), 256, 0, stream>>>(
        Wout, WoutT, 32000, 1024, 0, 0, flagp);
    prep_wo_kernel<<<4096, 256, 0, stream>>>(Wo, WoT, flagp);
    cvt_bias_kernel<<<4, 256, 0, stream>>>(bq, bqkvf, 1024, flagp);
    cvt_bias_kernel<<<4, 256, 0, stream>>>(bk_, bqkvf + 1024, 1024, flagp);
    cvt_bias_kernel<<<4, 256, 0, stream>>>(bv, bqkvf + 2048, 1024, flagp);
    cvt_bias_kernel<<<16, 256, 0, stream>>>(b1, b1f, 4096, flagp);
    cvt_bias_kernel<<<4, 256, 0, stream>>>(b2, b2f, 1024, flagp);
    cvt_bias_kernel<<<4, 256, 0, stream>>>(bo, bof, 1024, flagp);
    cvt_bias_kernel<<<125, 256, 0, stream>>>(bout, boutf, 32000, flagp);

    embed_kernel<<<4096, 256, 0, stream>>>(x, tok, pos, h, flagp);

    for (int layer = 0; layer < 4; ++layer) {
        ln_kernel<<<4096, 256, 0, stream>>>(h, ln1g, ln1b, xn, flagp);
        // fused QKV: [4096,1024] @ [1024,3072] -> [4096,3072]
        gemm_bt_kernel<false,false,false><<<dim3(32, 24), 256, 0, stream>>>(
            xn, 1024, WqkvT, bqkvf, qkvb, 3072, 1024, flagp);
        flash_kernel<<<dim3(16, 1, 64), 256, 0, stream>>>(qkvb, yb);
        // output projection via dense block-diagonal WoT + residual add
        gemm_bt_kernel<false,true,false><<<dim3(32, 8), 256, 0, stream>>>(
            yb, 1024, WoT, bof, h, 1024, 1024, flagp);
        ln_kernel<<<4096, 256, 0, stream>>>(h, ln2g, ln2b, xn, flagp);
        gemm_bt_kernel<true,false,false><<<dim3(32, 32), 256, 0, stream>>>(
            xn, 1024, W1T, b1f, mid, 4096, 1024, flagp);
        gemm_bt_kernel<false,true,false><<<dim3(32, 8), 256, 0, stream>>>(
            mid, 4096, W2T, b2f, h, 1024, 4096, flagp);
    }

    ln_kernel<<<4096, 256, 0, stream>>>(h, lnfg, lnfb, xn, flagp);
    gemm_bt_kernel<false,false,true><<<dim3(32, 250), 256, 0, stream>>>(
        xn, 1024, WoutT, boutf, d_out, 32000, 1024, flagp);
}